// Round 4
// baseline (19518.835 us; speedup 1.0000x reference)
//
#include <hip/hip_runtime.h>
#include <math.h>

// Dims
constexpr int BB  = 128;
constexpr int TT  = 512;
constexpr int DIN = 88;
constexpr int DZ  = 80;
constexpr int DH  = 400;
constexpr int DE  = 100;
constexpr int DTR = 200;
constexpr int DOUT = DIN + DZ + DZ; // 248
constexpr int TCH = 16;             // t-chunk for e_kernel / pre_kernel

// RNN W_hh partition (100 float4 k-chunks per row of W_hh). Wave-uniform roles:
//  wave 0   (tid   0.. 63): rows  0..63 : reg chunks 0..47; stream 96..99
//                           (helpers in wave 7 hold chunks 48..95)
//  wave 1   (tid  64..127): rows 64..127: reg chunks 0..47; stream 48..99
//  waves2-6 (tid 128..447): rows 128..399 (tid>=400 clamped/idle):
//                           reg 0..47; LDS 48..77; stream 78..99
//  wave 7   (tid 448..511): helper for row tid-448 (rows 0..63), reg chunks 48..95
constexpr int NREG  = 48;
constexpr int RL0   = 128;            // first row of the LDS-W region
constexpr int NLROWS = DH - RL0;      // 272
constexpr int NLDSC = 30;             // LDS chunks 48..77
constexpr int STRC0 = 78;             // stream chunks for rows>=128

__device__ __forceinline__ float dot4(float4 w, float4 h, float acc) {
    return fmaf(w.x, h.x, fmaf(w.y, h.y, fmaf(w.z, h.z, fmaf(w.w, h.w, acc))));
}
__device__ __forceinline__ float softplusf(float x) {
    return fmaxf(x, 0.f) + log1pf(__expf(-fabsf(x)));
}
__device__ __forceinline__ float sigmoidf(float x) {
    return 1.f / (1.f + __expf(-x));
}
#define PIN4(w) asm volatile("" : "+v"((w).x), "+v"((w).y), "+v"((w).z), "+v"((w).w))

// h[k] broadcast from per-lane regs via readlane (SGPR result, VALU pipe, no LDS)
#define HKV(K) __int_as_float(__builtin_amdgcn_readlane(__float_as_int(hl[(K) >> 6]), (K) & 63))
#define CHUNK4(W4, KB, ACC) do { \
    float4 _w = (W4); \
    ACC = fmaf(_w.x, HKV((KB) + 0), ACC); \
    ACC = fmaf(_w.y, HKV((KB) + 1), ACC); \
    ACC = fmaf(_w.z, HKV((KB) + 2), ACC); \
    ACC = fmaf(_w.w, HKV((KB) + 3), ACC); \
} while (0)

// Generic transpose-pack: dst[kk*dstStride + dstOff + o] = float4(src[o*K+4kk..])
__global__ void packt_kernel(const float* __restrict__ src, float4* __restrict__ dst,
                             int O, int K, int dstStride, int dstOff) {
    int idx = blockIdx.x * 256 + threadIdx.x;
    if (idx < O * (K / 4)) {
        int o = idx % O, kk = idx / O;
        const float* s = src + o * K + 4 * kk;
        dst[kk * dstStride + dstOff + o] = make_float4(s[0], s[1], s[2], s[3]);
    }
}

// pre[b][tt][h] = sum_k x[b][T-1-tt][k]*W_ih[h][k] + b_ih[h] + b_hh[h]
__global__ __launch_bounds__(256) void pre_kernel(
    const float* __restrict__ x, const float4* __restrict__ Wiht,
    const float* __restrict__ b_ih, const float* __restrict__ b_hh,
    float* __restrict__ pre) {
    int b = blockIdx.y;
    int tt0 = blockIdx.x * TCH;
    __shared__ float xs[TCH][DIN];
    int tid = threadIdx.x;
    for (int idx = tid; idx < TCH * DIN; idx += 256) {
        int r = idx / DIN, k = idx % DIN;
        int tsrc = TT - 1 - (tt0 + r);
        xs[r][k] = x[(b * TT + tsrc) * DIN + k];
    }
    __syncthreads();
    for (int h = tid; h < DH; h += 256) {
        float bias = b_ih[h] + b_hh[h];
        float acc[TCH];
        #pragma unroll
        for (int r = 0; r < TCH; ++r) acc[r] = bias;
        for (int kk = 0; kk < DIN / 4; ++kk) {
            float4 w = Wiht[kk * DH + h];
            #pragma unroll
            for (int r = 0; r < TCH; ++r) {
                float4 xv = *(const float4*)(&xs[r][4 * kk]);
                acc[r] = dot4(w, xv, acc[r]);
            }
        }
        for (int r = 0; r < TCH; ++r)
            pre[(size_t)(b * TT + tt0 + r) * DH + h] = acc[r];
    }
}

// Serial scan: h_t = relu(pre_t + W_hh h_{t-1}); writes h_t in-place over pre_t.
__global__ __launch_bounds__(512, 1) void rnn_kernel(
    const float4* __restrict__ Wpk, const float* __restrict__ h0,
    float* __restrict__ hs) {
    extern __shared__ float smem[];
    float4* Wl     = (float4*)smem;                  // [NLDSC][NLROWS] chunks 48..77
    float*  hcur   = smem + NLDSC * NLROWS * 4;      // 448 floats (400 + zero pad)
    float*  partial = hcur + 448;                    // 64 floats (helper partials)

    const int b = blockIdx.x, tid = threadIdx.x;
    const int lane = tid & 63;
    const bool isHelper = (tid >= 448);
    const int row  = isHelper ? (tid - 448) : tid;       // helper assists row tid-448
    const int rowc = (row < DH) ? row : (DH - 1);        // clamp for safe loads
    const int c0   = isHelper ? NREG : 0;

    // Register-resident W chunks (48 float4 = 192 VGPR), pinned against sinking.
    float4 W[NREG];
    #pragma unroll
    for (int c = 0; c < NREG; ++c) {
        float4 w = Wpk[(c0 + c) * DH + rowc];
        PIN4(w);
        W[c] = w;
    }

    for (int i = tid; i < NLDSC * NLROWS; i += 512) {
        int c = i / NLROWS, r = i % NLROWS;
        Wl[i] = Wpk[(NREG + c) * DH + (RL0 + r)];
    }
    if (tid < 448) hcur[tid] = (tid < DH) ? h0[tid] : 0.f;
    __syncthreads();

    float* base = hs + (size_t)b * TT * DH;
    float pre_cur = (tid < DH) ? base[row] : 0.f;

    for (int tt = 0; tt < TT; ++tt) {
        // per-lane h registers: hl[j] = h[64*j + lane]
        float hl[7];
        #pragma unroll
        for (int j = 0; j < 7; ++j) hl[j] = hcur[64 * j + lane];

        float pre_nxt = 0.f;
        if (tid < DH && tt + 1 < TT) pre_nxt = base[(tt + 1) * DH + row];

        float a[4] = {0.f, 0.f, 0.f, 0.f};
        if (tid < 64) {                       // rows 0..63: reg 0..47 + stream 96..99
            #pragma unroll
            for (int c = 0; c < NREG; ++c) CHUNK4(W[c], 4 * c, a[c & 3]);
            #pragma unroll
            for (int c = 96; c < 100; ++c) {
                float4 w = Wpk[c * DH + row];
                CHUNK4(w, 4 * c, a[c & 3]);
            }
        } else if (tid < 128) {               // rows 64..127: reg 0..47 + stream 48..99
            #pragma unroll
            for (int c = 0; c < NREG; ++c) CHUNK4(W[c], 4 * c, a[c & 3]);
            #pragma unroll
            for (int c = NREG; c < 100; ++c) {
                float4 w = Wpk[c * DH + row];
                CHUNK4(w, 4 * c, a[c & 3]);
            }
        } else if (!isHelper) {               // rows 128..447(clamped): reg+LDS+stream
            #pragma unroll
            for (int c = 0; c < NREG; ++c) CHUNK4(W[c], 4 * c, a[c & 3]);
            #pragma unroll
            for (int c = 0; c < NLDSC; ++c) {
                float4 w = Wl[c * NLROWS + (rowc - RL0)];
                CHUNK4(w, 4 * (NREG + c), a[c & 3]);
            }
            #pragma unroll
            for (int c = STRC0; c < 100; ++c) {
                float4 w = Wpk[c * DH + rowc];
                CHUNK4(w, 4 * c, a[c & 3]);
            }
        } else {                              // wave 7 helpers: chunks 48..95 of rows 0..63
            #pragma unroll
            for (int c = 0; c < NREG; ++c) CHUNK4(W[c], 4 * (NREG + c), a[c & 3]);
            partial[row] = (a[0] + a[1]) + (a[2] + a[3]);
        }
        __syncthreads();   // partials visible; all hl reads long done
        if (tid < DH) {
            float acc = pre_cur + (a[0] + a[1]) + (a[2] + a[3]);
            if (tid < 64) acc += partial[tid];
            float v = fmaxf(acc, 0.f);
            hcur[row] = v;
            base[tt * DH + row] = v;
            pre_cur = pre_nxt;
        }
        __syncthreads();   // hcur ready for next step
    }
}

// Fused downstream over (b, 16-t chunk). All weights packed transposed
// (coalesced lane=o), activations broadcast from LDS, 16-row reuse per weight.
__global__ __launch_bounds__(320, 3) void e_kernel(
    const float* __restrict__ hs, const float* __restrict__ eps,
    const float* __restrict__ z0,
    const float4* __restrict__ Wzt,   // [100][160] (part,o)
    const float* __restrict__ b_loc, const float* __restrict__ b_scale,
    const float4* __restrict__ g1t, const float* __restrict__ gb1,   // [20][200]
    const float4* __restrict__ p1t, const float* __restrict__ pb1,
    const float4* __restrict__ g2t, const float* __restrict__ gb2,   // [50][80]
    const float4* __restrict__ p2t, const float* __restrict__ pb2,
    const float4* __restrict__ lWt, const float* __restrict__ lb,    // [20][80]
    const float4* __restrict__ sWt, const float* __restrict__ sb,
    const float4* __restrict__ e1t, const float* __restrict__ eb1,   // [20][100]
    const float4* __restrict__ e2t, const float* __restrict__ eb2,   // [25][100]
    const float4* __restrict__ e3t, const float* __restrict__ eb3,   // [25][88]
    float* __restrict__ out) {
    __shared__ float u1[17 * DH];       // hsr[17][400] | A,P[16][200] | h1,h2[16][100]
    __shared__ float u2[2 * 17 * DZ];   // zpre[2][17][80] | gate,prop[16][80]
    __shared__ float zl[17][DZ];

    float (*hsr)[DH]  = (float(*)[DH])u1;
    float (*A)[DTR]   = (float(*)[DTR])u1;
    float (*P)[DTR]   = (float(*)[DTR])(u1 + 16 * DTR);
    float (*h1)[DE]   = (float(*)[DE])u1;
    float (*h2)[DE]   = (float(*)[DE])(u1 + 16 * DE);
    float (*gate)[DZ] = (float(*)[DZ])u2;
    float (*prop)[DZ] = (float(*)[DZ])(u2 + 16 * DZ);

    int b = blockIdx.y;
    int t0 = blockIdx.x * TCH;
    int tid = threadIdx.x;

    // P0: stage rnn_out rows r=0..16 <-> t=t0-1+r (hs index T-1-t)
    for (int idx = tid; idx < 17 * DH; idx += 320) {
        int r = idx / DH, k = idx % DH;
        int t = t0 - 1 + r;
        hsr[r][k] = (t >= 0) ? hs[((size_t)b * TT + (TT - 1 - t)) * DH + k] : 0.f;
    }
    __syncthreads();

    // P1: z pre-activations. 320 tasks = rh{0,1} x part{loc,scale} x o(80)
    {
        int rh = tid / 160, rem = tid % 160;      // rem = part*80+o
        int rbeg = rh ? 9 : 0, rend = rh ? 17 : 9;
        float bias = (rem < DZ) ? b_loc[rem] : b_scale[rem - DZ];
        float acc[9];
        #pragma unroll
        for (int i = 0; i < 9; ++i) acc[i] = bias;
        for (int kk = 0; kk < DH / 4; ++kk) {
            float4 w = Wzt[kk * 160 + rem];
            #pragma unroll
            for (int i = 0; i < 9; ++i) {
                if (rbeg + i < rend) {
                    float4 hv = *(const float4*)(&hsr[rbeg + i][4 * kk]);
                    acc[i] = dot4(w, hv, acc[i]);
                }
            }
        }
        int part = rem / DZ, o = rem % DZ;
        for (int i = 0; i < 9 && rbeg + i < rend; ++i)
            u2[part * (17 * DZ) + (rbeg + i) * DZ + o] = acc[i];
    }
    __syncthreads();

    // P1b: z = z_loc + softplus(z_scale_pre)*eps (row r=0 at t0=0 -> z0)
    for (int idx = tid; idx < 17 * DZ; idx += 320) {
        int r = idx / DZ, o = idx % DZ;
        int t = t0 - 1 + r;
        float zv;
        if (t < 0) zv = z0[o];
        else {
            float sp = softplusf(u2[17 * DZ + r * DZ + o]);
            zv = u2[r * DZ + o] + sp * eps[((size_t)b * TT + t) * DZ + o];
        }
        zl[r][o] = zv;
    }
    __syncthreads();

    // P2: A=relu(zs@gW1^T+gb1), P=relu(zs@pW1^T+pb1); zs row r -> zl[r]
    for (int task = tid; task < 2 * DTR; task += 320) {
        int rh = task / DTR, o = task % DTR;
        int rbeg = rh * 8;
        float accA[8], accP[8];
        float bg = gb1[o], bp = pb1[o];
        #pragma unroll
        for (int i = 0; i < 8; ++i) { accA[i] = bg; accP[i] = bp; }
        for (int kk = 0; kk < DZ / 4; ++kk) {
            float4 wg = g1t[kk * DTR + o];
            float4 wp = p1t[kk * DTR + o];
            #pragma unroll
            for (int i = 0; i < 8; ++i) {
                float4 zv = *(const float4*)(&zl[rbeg + i][4 * kk]);
                accA[i] = dot4(wg, zv, accA[i]);
                accP[i] = dot4(wp, zv, accP[i]);
            }
        }
        #pragma unroll
        for (int i = 0; i < 8; ++i) {
            A[rbeg + i][o] = fmaxf(accA[i], 0.f);
            P[rbeg + i][o] = fmaxf(accP[i], 0.f);
        }
    }
    __syncthreads();

    // P3: gate = sigmoid(A@gW2^T+gb2); prop = P@pW2^T+pb2. 320 tasks.
    {
        int o = tid % DZ, mr = tid / DZ;
        int mat = mr >> 1, rh = mr & 1, rbeg = rh * 8;
        const float4* Wt = mat ? p2t : g2t;
        float bias = mat ? pb2[o] : gb2[o];
        float acc[8];
        #pragma unroll
        for (int i = 0; i < 8; ++i) acc[i] = bias;
        for (int kk = 0; kk < DTR / 4; ++kk) {
            float4 w = Wt[kk * DZ + o];
            #pragma unroll
            for (int i = 0; i < 8; ++i) {
                const float* src = mat ? &P[rbeg + i][4 * kk] : &A[rbeg + i][4 * kk];
                float4 v = *(const float4*)src;
                acc[i] = dot4(w, v, acc[i]);
            }
        }
        for (int i = 0; i < 8; ++i) {
            if (mat) prop[rbeg + i][o] = acc[i];
            else     gate[rbeg + i][o] = sigmoidf(acc[i]);
        }
    }
    __syncthreads();

    // P4: trans_loc / trans_scale -> out[88..248)
    {
        int o = tid % DZ, wr = tid / DZ;
        int which = wr >> 1, rh = wr & 1, rbeg = rh * 8;
        float acc[8];
        if (which == 0) {
            float bias = lb[o];
            #pragma unroll
            for (int i = 0; i < 8; ++i) acc[i] = bias;
            for (int kk = 0; kk < DZ / 4; ++kk) {
                float4 w = lWt[kk * DZ + o];
                #pragma unroll
                for (int i = 0; i < 8; ++i) {
                    float4 zv = *(const float4*)(&zl[rbeg + i][4 * kk]);
                    acc[i] = dot4(w, zv, acc[i]);
                }
            }
            for (int i = 0; i < 8; ++i) {
                int r = rbeg + i;
                float g = gate[r][o];
                float tl = (1.f - g) * acc[i] + g * prop[r][o];
                out[((size_t)b * TT + t0 + r) * DOUT + DIN + o] = tl;
            }
        } else {
            float bias = sb[o];
            #pragma unroll
            for (int i = 0; i < 8; ++i) acc[i] = bias;
            for (int kk = 0; kk < DZ / 4; ++kk) {
                float4 w = sWt[kk * DZ + o];
                #pragma unroll
                for (int i = 0; i < 8; ++i) {
                    float4 pv = *(const float4*)(&prop[rbeg + i][4 * kk]);
                    pv.x = fmaxf(pv.x, 0.f); pv.y = fmaxf(pv.y, 0.f);
                    pv.z = fmaxf(pv.z, 0.f); pv.w = fmaxf(pv.w, 0.f);
                    acc[i] = dot4(w, pv, acc[i]);
                }
            }
            for (int i = 0; i < 8; ++i)
                out[((size_t)b * TT + t0 + rbeg + i) * DOUT + DIN + DZ + o] = softplusf(acc[i]);
        }
    }
    __syncthreads();

    // P5: h1 = relu(z@eW1^T+eb1); z row for t=t0+r is zl[r+1]
    for (int task = tid; task < 2 * DE; task += 320) {
        int rh = task / DE, o = task % DE, rbeg = rh * 8;
        float acc[8];
        float bias = eb1[o];
        #pragma unroll
        for (int i = 0; i < 8; ++i) acc[i] = bias;
        for (int kk = 0; kk < DZ / 4; ++kk) {
            float4 w = e1t[kk * DE + o];
            #pragma unroll
            for (int i = 0; i < 8; ++i) {
                float4 zv = *(const float4*)(&zl[rbeg + i + 1][4 * kk]);
                acc[i] = dot4(w, zv, acc[i]);
            }
        }
        for (int i = 0; i < 8; ++i) h1[rbeg + i][o] = fmaxf(acc[i], 0.f);
    }
    __syncthreads();

    // P6: h2 = relu(h1@eW2^T+eb2)
    for (int task = tid; task < 2 * DE; task += 320) {
        int rh = task / DE, o = task % DE, rbeg = rh * 8;
        float acc[8];
        float bias = eb2[o];
        #pragma unroll
        for (int i = 0; i < 8; ++i) acc[i] = bias;
        for (int kk = 0; kk < DE / 4; ++kk) {
            float4 w = e2t[kk * DE + o];
            #pragma unroll
            for (int i = 0; i < 8; ++i) {
                float4 hv = *(const float4*)(&h1[rbeg + i][4 * kk]);
                acc[i] = dot4(w, hv, acc[i]);
            }
        }
        for (int i = 0; i < 8; ++i) h2[rbeg + i][o] = fmaxf(acc[i], 0.f);
    }
    __syncthreads();

    // P7: emis = sigmoid(h2@eW3^T+eb3) -> out[0..88)
    for (int task = tid; task < 2 * DIN; task += 320) {
        int rh = task / DIN, o = task % DIN, rbeg = rh * 8;
        float acc[8];
        float bias = eb3[o];
        #pragma unroll
        for (int i = 0; i < 8; ++i) acc[i] = bias;
        for (int kk = 0; kk < DE / 4; ++kk) {
            float4 w = e3t[kk * DIN + o];
            #pragma unroll
            for (int i = 0; i < 8; ++i) {
                float4 hv = *(const float4*)(&h2[rbeg + i][4 * kk]);
                acc[i] = dot4(w, hv, acc[i]);
            }
        }
        for (int i = 0; i < 8; ++i)
            out[((size_t)b * TT + t0 + rbeg + i) * DOUT + o] = sigmoidf(acc[i]);
    }
}

static inline void packt(const float* src, float4* dst, int O, int K,
                         int stride, int off, hipStream_t stream) {
    int total = O * (K / 4);
    packt_kernel<<<(total + 255) / 256, 256, 0, stream>>>(src, dst, O, K, stride, off);
}

extern "C" void kernel_launch(void* const* d_in, const int* in_sizes, int n_in,
                              void* d_out, int out_size, void* d_ws, size_t ws_size,
                              hipStream_t stream) {
    const float* x       = (const float*)d_in[0];
    const float* eps     = (const float*)d_in[1];
    const float* W_ih    = (const float*)d_in[2];
    const float* W_hh    = (const float*)d_in[3];
    const float* b_ih    = (const float*)d_in[4];
    const float* b_hh    = (const float*)d_in[5];
    const float* h0      = (const float*)d_in[6];
    const float* z0      = (const float*)d_in[7];
    const float* W_loc   = (const float*)d_in[8];
    const float* b_loc   = (const float*)d_in[9];
    const float* W_scale = (const float*)d_in[10];
    const float* b_scale = (const float*)d_in[11];
    const float* gW1 = (const float*)d_in[12];
    const float* gb1 = (const float*)d_in[13];
    const float* gW2 = (const float*)d_in[14];
    const float* gb2 = (const float*)d_in[15];
    const float* pW1 = (const float*)d_in[16];
    const float* pb1 = (const float*)d_in[17];
    const float* pW2 = (const float*)d_in[18];
    const float* pb2 = (const float*)d_in[19];
    const float* sW  = (const float*)d_in[20];
    const float* sb  = (const float*)d_in[21];
    const float* lW  = (const float*)d_in[22];
    const float* lb  = (const float*)d_in[23];
    const float* eW1 = (const float*)d_in[24];
    const float* eb1 = (const float*)d_in[25];
    const float* eW2 = (const float*)d_in[26];
    const float* eb2 = (const float*)d_in[27];
    const float* eW3 = (const float*)d_in[28];
    const float* eb3 = (const float*)d_in[29];

    float* wsf = (float*)d_ws;
    float* prebuf = wsf;                                  // B*T*H floats
    float4* pk = (float4*)(wsf + (size_t)BB * TT * DH);   // packed weights
    float4* Wpk  = pk;            // 40000
    float4* Wzt  = pk + 40000;    // 16000 [100][160]
    float4* g1t  = pk + 56000;    // 4000  [20][200]
    float4* p1t  = pk + 60000;    // 4000
    float4* g2t  = pk + 64000;    // 4000  [50][80]
    float4* p2t  = pk + 68000;    // 4000
    float4* lWt  = pk + 72000;    // 1600  [20][80]
    float4* sWt  = pk + 73600;    // 1600
    float4* e1t  = pk + 75200;    // 2000  [20][100]
    float4* e2t  = pk + 77200;    // 2500  [25][100]
    float4* e3t  = pk + 79700;    // 2200  [25][88]
    float4* Wiht = pk + 81900;    // 8800  [22][400]

    packt(W_hh,    Wpk,  DH,  DH,  DH,  0,  stream);
    packt(W_loc,   Wzt,  DZ,  DH,  160, 0,  stream);
    packt(W_scale, Wzt,  DZ,  DH,  160, DZ, stream);
    packt(gW1,     g1t,  DTR, DZ,  DTR, 0,  stream);
    packt(pW1,     p1t,  DTR, DZ,  DTR, 0,  stream);
    packt(gW2,     g2t,  DZ,  DTR, DZ,  0,  stream);
    packt(pW2,     p2t,  DZ,  DTR, DZ,  0,  stream);
    packt(lW,      lWt,  DZ,  DZ,  DZ,  0,  stream);
    packt(sW,      sWt,  DZ,  DZ,  DZ,  0,  stream);
    packt(eW1,     e1t,  DE,  DZ,  DE,  0,  stream);
    packt(eW2,     e2t,  DE,  DE,  DE,  0,  stream);
    packt(eW3,     e3t,  DIN, DE,  DIN, 0,  stream);
    packt(W_ih,    Wiht, DH,  DIN, DH,  0,  stream);

    pre_kernel<<<dim3(TT / TCH, BB), 256, 0, stream>>>(x, Wiht, b_ih, b_hh, prebuf);

    size_t smem = (size_t)NLDSC * NLROWS * sizeof(float4)
                + 448 * sizeof(float) + 64 * sizeof(float);
    hipFuncSetAttribute((const void*)rnn_kernel,
                        hipFuncAttributeMaxDynamicSharedMemorySize, (int)smem);
    rnn_kernel<<<dim3(BB), dim3(512), smem, stream>>>(Wpk, h0, prebuf);

    e_kernel<<<dim3(TT / TCH, BB), 320, 0, stream>>>(
        prebuf, eps, z0, Wzt, b_loc, b_scale,
        g1t, gb1, p1t, pb1, g2t, gb2, p2t, pb2,
        lWt, lb, sWt, sb, e1t, eb1, e2t, eb2, e3t, eb3, (float*)d_out);
}

// Round 5
// 1987.305 us; speedup vs baseline: 9.8218x; 9.8218x over previous
//
#include <hip/hip_runtime.h>
#include <math.h>

typedef unsigned int uint;
typedef unsigned short ushort;

// Dims
constexpr int BB  = 128;
constexpr int TT  = 512;
constexpr int DIN = 88;
constexpr int DZ  = 80;
constexpr int DH  = 400;
constexpr int DE  = 100;
constexpr int DTR = 200;
constexpr int DOUT = DIN + DZ + DZ; // 248
constexpr int TCH = 16;

__device__ __forceinline__ float dot4(float4 w, float4 h, float acc) {
    return fmaf(w.x, h.x, fmaf(w.y, h.y, fmaf(w.z, h.z, fmaf(w.w, h.w, acc))));
}
__device__ __forceinline__ float softplusf(float x) {
    return fmaxf(x, 0.f) + log1pf(__expf(-fabsf(x)));
}
__device__ __forceinline__ float sigmoidf(float x) {
    return 1.f / (1.f + __expf(-x));
}
__device__ __forceinline__ uint bf16rn(float f) {
    uint u = __float_as_uint(f);
    return (u + 0x7FFFu + ((u >> 16) & 1u)) >> 16;
}
__device__ __forceinline__ uint pk2(float lo, float hi) {
    return bf16rn(lo) | (bf16rn(hi) << 16);
}
// v_dot2_f32_bf16: ACC += W.lo*H.lo + W.hi*H.hi (bf16 pairs, fp32 accumulate)
#define DOT2(ACC, Wv, Hv) asm("v_dot2_f32_bf16 %0, %1, %2, %0" : "+v"(ACC) : "v"(Wv), "v"(Hv))

// ---------------- weight pack kernels ----------------

// Generic transpose-pack: dst[kk*dstStride + dstOff + o] = float4(src[o*K+4kk..])
__global__ void packt_kernel(const float* __restrict__ src, float4* __restrict__ dst,
                             int O, int K, int dstStride, int dstOff) {
    int idx = blockIdx.x * 256 + threadIdx.x;
    if (idx < O * (K / 4)) {
        int o = idx % O, kk = idx / O;
        const float* s = src + o * K + 4 * kk;
        dst[kk * dstStride + dstOff + o] = make_float4(s[0], s[1], s[2], s[3]);
    }
}

// Pack W_hh into per-thread bf16-pair dwords for the rnn kernel.
// Thread roles: tid<200 -> (p=tid, hf=0, k 0..199); 256<=tid<456 -> (p=tid-256, hf=1, k 200..399).
// Thread's dword j (0..199): row = 2p + (j>=100), k-dword = hf*100 + j%100.
// Stored as uint4-interleaved: Wb[(j>>2)*2048 + t*4 + (j&3)]
__global__ void pack_rnn(const float* __restrict__ W_hh, uint* __restrict__ Wb) {
    int idx = blockIdx.x * 256 + threadIdx.x;
    if (idx >= 200 * 512) return;
    int t = idx & 511, j = idx >> 9;
    uint val = 0u;
    int p = -1, hf = 0;
    if (t < 200) { p = t; hf = 0; }
    else if (t >= 256 && t < 456) { p = t - 256; hf = 1; }
    if (p >= 0) {
        int r  = 2 * p + (j >= 100 ? 1 : 0);
        int kd = hf * 100 + (j % 100);
        val = pk2(W_hh[r * DH + 2 * kd], W_hh[r * DH + 2 * kd + 1]);
    }
    Wb[(j >> 2) * 2048 + t * 4 + (j & 3)] = val;
}

// ---------------- pre GEMM ----------------

__global__ __launch_bounds__(256) void pre_kernel(
    const float* __restrict__ x, const float4* __restrict__ Wiht,
    const float* __restrict__ b_ih, const float* __restrict__ b_hh,
    float* __restrict__ pre) {
    int b = blockIdx.y;
    int tt0 = blockIdx.x * TCH;
    __shared__ float xs[TCH][DIN];
    int tid = threadIdx.x;
    for (int idx = tid; idx < TCH * DIN; idx += 256) {
        int r = idx / DIN, k = idx % DIN;
        int tsrc = TT - 1 - (tt0 + r);
        xs[r][k] = x[(b * TT + tsrc) * DIN + k];
    }
    __syncthreads();
    for (int h = tid; h < DH; h += 256) {
        float bias = b_ih[h] + b_hh[h];
        float acc[TCH];
        #pragma unroll
        for (int r = 0; r < TCH; ++r) acc[r] = bias;
        for (int kk = 0; kk < DIN / 4; ++kk) {
            float4 w = Wiht[kk * DH + h];
            #pragma unroll
            for (int r = 0; r < TCH; ++r) {
                float4 xv = *(const float4*)(&xs[r][4 * kk]);
                acc[r] = dot4(w, xv, acc[r]);
            }
        }
        for (int r = 0; r < TCH; ++r)
            pre[(size_t)(b * TT + tt0 + r) * DH + h] = acc[r];
    }
}

// ---------------- serial RNN scan ----------------
// h_t = relu(pre_t + W_hh h_{t-1}). W_hh entirely register-resident as bf16 pairs.
// Writes h_t packed-bf16 into the first 200 dwords of the consumed pre row.

#define DLOOP(OFF)                                                              \
    _Pragma("unroll")                                                           \
    for (int d = 0; d < 100; ++d) {                                             \
        const int kd = (OFF) + d;                                               \
        const int hsrc = ((kd >> 6) == 0) ? hl0 : ((kd >> 6) == 1) ? hl1        \
                        : ((kd >> 6) == 2) ? hl2 : hl3;                         \
        int hv = __builtin_amdgcn_readlane(hsrc, kd & 63);                      \
        if (d & 1) { DOT2(r0b, W[d], hv); DOT2(r1b, W[100 + d], hv); }          \
        else       { DOT2(r0a, W[d], hv); DOT2(r1a, W[100 + d], hv); }          \
    }

__global__ __launch_bounds__(512) __attribute__((amdgpu_waves_per_eu(2, 2)))
void rnn_kernel(const uint* __restrict__ Wb, const float* __restrict__ h0,
                float* hs) {
    __shared__ uint h_lds[256];     // packed bf16 pairs: dword p = (h[2p], h[2p+1]); 200..255 zero
    __shared__ float2 part[200];    // hf=1 partial sums per row-pair

    const int tid = threadIdx.x;
    const int lane = tid & 63;
    const bool a0 = (tid < 200);
    const bool a1 = (tid >= 256) && (tid < 456);
    const int p = a0 ? tid : (a1 ? tid - 256 : 0);

    // Whole W_hh in registers: 200 packed dwords = 2 rows x 200 k-dwords.
    uint W[200];
    const uint4* Wb4 = (const uint4*)Wb;
    #pragma unroll
    for (int j4 = 0; j4 < 50; ++j4) {
        uint4 v = Wb4[j4 * 512 + tid];
        W[4 * j4 + 0] = v.x; W[4 * j4 + 1] = v.y;
        W[4 * j4 + 2] = v.z; W[4 * j4 + 3] = v.w;
    }
    #pragma unroll
    for (int j = 0; j < 200; ++j) asm volatile("" : "+v"(W[j]));

    if (tid < 256)
        h_lds[tid] = (tid < 200) ? pk2(h0[2 * tid], h0[2 * tid + 1]) : 0u;
    __syncthreads();

    float* base = hs + (size_t)blockIdx.x * TT * DH;
    float2 pcur = make_float2(0.f, 0.f);
    if (a0) pcur = *(const float2*)(base + 2 * p);

    for (int tt = 0; tt < TT; ++tt) {
        // broadcast source regs: hl[j] = h dword (64*j + lane); loaded by ALL threads
        int hl0 = (int)h_lds[lane];
        int hl1 = (int)h_lds[64 + lane];
        int hl2 = (int)h_lds[128 + lane];
        int hl3 = (int)h_lds[192 + lane];

        float2 pnxt = make_float2(0.f, 0.f);
        if (a0 && tt + 1 < TT) pnxt = *(const float2*)(base + (size_t)(tt + 1) * DH + 2 * p);

        float r0a = 0.f, r0b = 0.f, r1a = 0.f, r1b = 0.f;
        if (a0)      { DLOOP(0) }
        else if (a1) { DLOOP(100) }

        if (a1) part[p] = make_float2(r0a + r0b, r1a + r1b);
        __syncthreads();   // partials visible; all h_lds reads of this step done
        if (a0) {
            float2 q = part[p];
            float v0 = fmaxf(pcur.x + r0a + r0b + q.x, 0.f);
            float v1 = fmaxf(pcur.y + r1a + r1b + q.y, 0.f);
            uint pkd = pk2(v0, v1);
            h_lds[p] = pkd;
            ((uint*)(base + (size_t)tt * DH))[p] = pkd;   // hs (bf16) over consumed pre
            pcur = pnxt;
        }
        __syncthreads();   // h_lds ready for next step
    }
}

// ---------------- fused downstream ----------------
// hs is now packed bf16: dword d of a row = (h[2d], h[2d+1]); row stride 400 floats (100 uint4).

__global__ __launch_bounds__(320, 3) void e_kernel(
    const uint4* __restrict__ hs4, const float* __restrict__ eps,
    const float* __restrict__ z0,
    const float4* __restrict__ Wzt,   // [100][160] (part,o)
    const float* __restrict__ b_loc, const float* __restrict__ b_scale,
    const float4* __restrict__ g1t, const float* __restrict__ gb1,   // [20][200]
    const float4* __restrict__ p1t, const float* __restrict__ pb1,
    const float4* __restrict__ g2t, const float* __restrict__ gb2,   // [50][80]
    const float4* __restrict__ p2t, const float* __restrict__ pb2,
    const float4* __restrict__ lWt, const float* __restrict__ lb,    // [20][80]
    const float4* __restrict__ sWt, const float* __restrict__ sb,
    const float4* __restrict__ e1t, const float* __restrict__ eb1,   // [20][100]
    const float4* __restrict__ e2t, const float* __restrict__ eb2,   // [25][100]
    const float4* __restrict__ e3t, const float* __restrict__ eb3,   // [25][88]
    float* __restrict__ out) {
    __shared__ float u1[17 * DH];       // hsr[17][400] | A,P[16][200] | h1,h2[16][100]
    __shared__ float u2[2 * 17 * DZ];   // zpre[2][17][80] | gate,prop[16][80]
    __shared__ float zl[17][DZ];

    float (*hsr)[DH]  = (float(*)[DH])u1;
    float (*A)[DTR]   = (float(*)[DTR])u1;
    float (*P)[DTR]   = (float(*)[DTR])(u1 + 16 * DTR);
    float (*h1)[DE]   = (float(*)[DE])u1;
    float (*h2)[DE]   = (float(*)[DE])(u1 + 16 * DE);
    float (*gate)[DZ] = (float(*)[DZ])u2;
    float (*prop)[DZ] = (float(*)[DZ])(u2 + 16 * DZ);

    int b = blockIdx.y;
    int t0 = blockIdx.x * TCH;
    int tid = threadIdx.x;

    // P0: stage rnn_out rows r=0..16 <-> t=t0-1+r (hs index T-1-t); unpack bf16
    for (int idx = tid; idx < 17 * 50; idx += 320) {
        int r = idx / 50, q = idx % 50;
        int t = t0 - 1 + r;
        uint4 v = {0u, 0u, 0u, 0u};
        if (t >= 0) v = hs4[((size_t)b * TT + (TT - 1 - t)) * 100 + q];
        int kb = q * 8;
        hsr[r][kb + 0] = __uint_as_float(v.x << 16);
        hsr[r][kb + 1] = __uint_as_float(v.x & 0xFFFF0000u);
        hsr[r][kb + 2] = __uint_as_float(v.y << 16);
        hsr[r][kb + 3] = __uint_as_float(v.y & 0xFFFF0000u);
        hsr[r][kb + 4] = __uint_as_float(v.z << 16);
        hsr[r][kb + 5] = __uint_as_float(v.z & 0xFFFF0000u);
        hsr[r][kb + 6] = __uint_as_float(v.w << 16);
        hsr[r][kb + 7] = __uint_as_float(v.w & 0xFFFF0000u);
    }
    __syncthreads();

    // P1: z pre-activations. 320 tasks = rh{0,1} x part{loc,scale} x o(80)
    {
        int rh = tid / 160, rem = tid % 160;
        int rbeg = rh ? 9 : 0, rend = rh ? 17 : 9;
        float bias = (rem < DZ) ? b_loc[rem] : b_scale[rem - DZ];
        float acc[9];
        #pragma unroll
        for (int i = 0; i < 9; ++i) acc[i] = bias;
        for (int kk = 0; kk < DH / 4; ++kk) {
            float4 w = Wzt[kk * 160 + rem];
            #pragma unroll
            for (int i = 0; i < 9; ++i) {
                if (rbeg + i < rend) {
                    float4 hv = *(const float4*)(&hsr[rbeg + i][4 * kk]);
                    acc[i] = dot4(w, hv, acc[i]);
                }
            }
        }
        int part = rem / DZ, o = rem % DZ;
        for (int i = 0; i < 9 && rbeg + i < rend; ++i)
            u2[part * (17 * DZ) + (rbeg + i) * DZ + o] = acc[i];
    }
    __syncthreads();

    // P1b: z = z_loc + softplus(z_scale_pre)*eps (row r=0 at t0=0 -> z0)
    for (int idx = tid; idx < 17 * DZ; idx += 320) {
        int r = idx / DZ, o = idx % DZ;
        int t = t0 - 1 + r;
        float zv;
        if (t < 0) zv = z0[o];
        else {
            float sp = softplusf(u2[17 * DZ + r * DZ + o]);
            zv = u2[r * DZ + o] + sp * eps[((size_t)b * TT + t) * DZ + o];
        }
        zl[r][o] = zv;
    }
    __syncthreads();

    // P2: A=relu(zs@gW1^T+gb1), P=relu(zs@pW1^T+pb1)
    for (int task = tid; task < 2 * DTR; task += 320) {
        int rh = task / DTR, o = task % DTR;
        int rbeg = rh * 8;
        float accA[8], accP[8];
        float bg = gb1[o], bp = pb1[o];
        #pragma unroll
        for (int i = 0; i < 8; ++i) { accA[i] = bg; accP[i] = bp; }
        for (int kk = 0; kk < DZ / 4; ++kk) {
            float4 wg = g1t[kk * DTR + o];
            float4 wp = p1t[kk * DTR + o];
            #pragma unroll
            for (int i = 0; i < 8; ++i) {
                float4 zv = *(const float4*)(&zl[rbeg + i][4 * kk]);
                accA[i] = dot4(wg, zv, accA[i]);
                accP[i] = dot4(wp, zv, accP[i]);
            }
        }
        #pragma unroll
        for (int i = 0; i < 8; ++i) {
            A[rbeg + i][o] = fmaxf(accA[i], 0.f);
            P[rbeg + i][o] = fmaxf(accP[i], 0.f);
        }
    }
    __syncthreads();

    // P3: gate = sigmoid(A@gW2^T+gb2); prop = P@pW2^T+pb2
    {
        int o = tid % DZ, mr = tid / DZ;
        int mat = mr >> 1, rh = mr & 1, rbeg = rh * 8;
        const float4* Wt = mat ? p2t : g2t;
        float bias = mat ? pb2[o] : gb2[o];
        float acc[8];
        #pragma unroll
        for (int i = 0; i < 8; ++i) acc[i] = bias;
        for (int kk = 0; kk < DTR / 4; ++kk) {
            float4 w = Wt[kk * DZ + o];
            #pragma unroll
            for (int i = 0; i < 8; ++i) {
                const float* src = mat ? &P[rbeg + i][4 * kk] : &A[rbeg + i][4 * kk];
                float4 v = *(const float4*)src;
                acc[i] = dot4(w, v, acc[i]);
            }
        }
        for (int i = 0; i < 8; ++i) {
            if (mat) prop[rbeg + i][o] = acc[i];
            else     gate[rbeg + i][o] = sigmoidf(acc[i]);
        }
    }
    __syncthreads();

    // P4: trans_loc / trans_scale -> out[88..248)
    {
        int o = tid % DZ, wr = tid / DZ;
        int which = wr >> 1, rh = wr & 1, rbeg = rh * 8;
        float acc[8];
        if (which == 0) {
            float bias = lb[o];
            #pragma unroll
            for (int i = 0; i < 8; ++i) acc[i] = bias;
            for (int kk = 0; kk < DZ / 4; ++kk) {
                float4 w = lWt[kk * DZ + o];
                #pragma unroll
                for (int i = 0; i < 8; ++i) {
                    float4 zv = *(const float4*)(&zl[rbeg + i][4 * kk]);
                    acc[i] = dot4(w, zv, acc[i]);
                }
            }
            for (int i = 0; i < 8; ++i) {
                int r = rbeg + i;
                float g = gate[r][o];
                float tl = (1.f - g) * acc[i] + g * prop[r][o];
                out[((size_t)b * TT + t0 + r) * DOUT + DIN + o] = tl;
            }
        } else {
            float bias = sb[o];
            #pragma unroll
            for (int i = 0; i < 8; ++i) acc[i] = bias;
            for (int kk = 0; kk < DZ / 4; ++kk) {
                float4 w = sWt[kk * DZ + o];
                #pragma unroll
                for (int i = 0; i < 8; ++i) {
                    float4 pv = *(const float4*)(&prop[rbeg + i][4 * kk]);
                    pv.x = fmaxf(pv.x, 0.f); pv.y = fmaxf(pv.y, 0.f);
                    pv.z = fmaxf(pv.z, 0.f); pv.w = fmaxf(pv.w, 0.f);
                    acc[i] = dot4(w, pv, acc[i]);
                }
            }
            for (int i = 0; i < 8; ++i)
                out[((size_t)b * TT + t0 + rbeg + i) * DOUT + DIN + DZ + o] = softplusf(acc[i]);
        }
    }
    __syncthreads();

    // P5: h1 = relu(z@eW1^T+eb1); z row for t=t0+r is zl[r+1]
    for (int task = tid; task < 2 * DE; task += 320) {
        int rh = task / DE, o = task % DE, rbeg = rh * 8;
        float acc[8];
        float bias = eb1[o];
        #pragma unroll
        for (int i = 0; i < 8; ++i) acc[i] = bias;
        for (int kk = 0; kk < DZ / 4; ++kk) {
            float4 w = e1t[kk * DE + o];
            #pragma unroll
            for (int i = 0; i < 8; ++i) {
                float4 zv = *(const float4*)(&zl[rbeg + i + 1][4 * kk]);
                acc[i] = dot4(w, zv, acc[i]);
            }
        }
        for (int i = 0; i < 8; ++i) h1[rbeg + i][o] = fmaxf(acc[i], 0.f);
    }
    __syncthreads();

    // P6: h2 = relu(h1@eW2^T+eb2)
    for (int task = tid; task < 2 * DE; task += 320) {
        int rh = task / DE, o = task % DE, rbeg = rh * 8;
        float acc[8];
        float bias = eb2[o];
        #pragma unroll
        for (int i = 0; i < 8; ++i) acc[i] = bias;
        for (int kk = 0; kk < DE / 4; ++kk) {
            float4 w = e2t[kk * DE + o];
            #pragma unroll
            for (int i = 0; i < 8; ++i) {
                float4 hv = *(const float4*)(&h1[rbeg + i][4 * kk]);
                acc[i] = dot4(w, hv, acc[i]);
            }
        }
        for (int i = 0; i < 8; ++i) h2[rbeg + i][o] = fmaxf(acc[i], 0.f);
    }
    __syncthreads();

    // P7: emis = sigmoid(h2@eW3^T+eb3) -> out[0..88)
    for (int task = tid; task < 2 * DIN; task += 320) {
        int rh = task / DIN, o = task % DIN, rbeg = rh * 8;
        float acc[8];
        float bias = eb3[o];
        #pragma unroll
        for (int i = 0; i < 8; ++i) acc[i] = bias;
        for (int kk = 0; kk < DE / 4; ++kk) {
            float4 w = e3t[kk * DIN + o];
            #pragma unroll
            for (int i = 0; i < 8; ++i) {
                float4 hv = *(const float4*)(&h2[rbeg + i][4 * kk]);
                acc[i] = dot4(w, hv, acc[i]);
            }
        }
        for (int i = 0; i < 8; ++i)
            out[((size_t)b * TT + t0 + rbeg + i) * DOUT + o] = sigmoidf(acc[i]);
    }
}

static inline void packt(const float* src, float4* dst, int O, int K,
                         int stride, int off, hipStream_t stream) {
    int total = O * (K / 4);
    packt_kernel<<<(total + 255) / 256, 256, 0, stream>>>(src, dst, O, K, stride, off);
}

extern "C" void kernel_launch(void* const* d_in, const int* in_sizes, int n_in,
                              void* d_out, int out_size, void* d_ws, size_t ws_size,
                              hipStream_t stream) {
    const float* x       = (const float*)d_in[0];
    const float* eps     = (const float*)d_in[1];
    const float* W_ih    = (const float*)d_in[2];
    const float* W_hh    = (const float*)d_in[3];
    const float* b_ih    = (const float*)d_in[4];
    const float* b_hh    = (const float*)d_in[5];
    const float* h0      = (const float*)d_in[6];
    const float* z0      = (const float*)d_in[7];
    const float* W_loc   = (const float*)d_in[8];
    const float* b_loc   = (const float*)d_in[9];
    const float* W_scale = (const float*)d_in[10];
    const float* b_scale = (const float*)d_in[11];
    const float* gW1 = (const float*)d_in[12];
    const float* gb1 = (const float*)d_in[13];
    const float* gW2 = (const float*)d_in[14];
    const float* gb2 = (const float*)d_in[15];
    const float* pW1 = (const float*)d_in[16];
    const float* pb1 = (const float*)d_in[17];
    const float* pW2 = (const float*)d_in[18];
    const float* pb2 = (const float*)d_in[19];
    const float* sW  = (const float*)d_in[20];
    const float* sb  = (const float*)d_in[21];
    const float* lW  = (const float*)d_in[22];
    const float* lb  = (const float*)d_in[23];
    const float* eW1 = (const float*)d_in[24];
    const float* eb1 = (const float*)d_in[25];
    const float* eW2 = (const float*)d_in[26];
    const float* eb2 = (const float*)d_in[27];
    const float* eW3 = (const float*)d_in[28];
    const float* eb3 = (const float*)d_in[29];

    float* wsf = (float*)d_ws;
    float* prebuf = wsf;                                  // B*T*DH floats (pre, then hs-bf16)
    float4* pk = (float4*)(wsf + (size_t)BB * TT * DH);   // packed weights
    uint*   Wb   = (uint*)pk;     // 102400 dwords (25600 float4-slots) rnn W
    float4* Wzt  = pk + 40000;    // 16000 [100][160]
    float4* g1t  = pk + 56000;    // 4000  [20][200]
    float4* p1t  = pk + 60000;    // 4000
    float4* g2t  = pk + 64000;    // 4000  [50][80]
    float4* p2t  = pk + 68000;    // 4000
    float4* lWt  = pk + 72000;    // 1600  [20][80]
    float4* sWt  = pk + 73600;    // 1600
    float4* e1t  = pk + 75200;    // 2000  [20][100]
    float4* e2t  = pk + 77200;    // 2500  [25][100]
    float4* e3t  = pk + 79700;    // 2200  [25][88]
    float4* Wiht = pk + 81900;    // 8800  [22][400]

    pack_rnn<<<(200 * 512 + 255) / 256, 256, 0, stream>>>(W_hh, Wb);
    packt(W_loc,   Wzt,  DZ,  DH,  160, 0,  stream);
    packt(W_scale, Wzt,  DZ,  DH,  160, DZ, stream);
    packt(gW1,     g1t,  DTR, DZ,  DTR, 0,  stream);
    packt(pW1,     p1t,  DTR, DZ,  DTR, 0,  stream);
    packt(gW2,     g2t,  DZ,  DTR, DZ,  0,  stream);
    packt(pW2,     p2t,  DZ,  DTR, DZ,  0,  stream);
    packt(lW,      lWt,  DZ,  DZ,  DZ,  0,  stream);
    packt(sW,      sWt,  DZ,  DZ,  DZ,  0,  stream);
    packt(eW1,     e1t,  DE,  DZ,  DE,  0,  stream);
    packt(eW2,     e2t,  DE,  DE,  DE,  0,  stream);
    packt(eW3,     e3t,  DIN, DE,  DIN, 0,  stream);
    packt(W_ih,    Wiht, DH,  DIN, DH,  0,  stream);

    pre_kernel<<<dim3(TT / TCH, BB), 256, 0, stream>>>(x, Wiht, b_ih, b_hh, prebuf);

    rnn_kernel<<<dim3(BB), dim3(512), 0, stream>>>(Wb, h0, prebuf);

    e_kernel<<<dim3(TT / TCH, BB), 320, 0, stream>>>(
        (const uint4*)prebuf, eps, z0, Wzt, b_loc, b_scale,
        g1t, gb1, p1t, pb1, g2t, gb2, p2t, pb2,
        lWt, lb, sWt, sb, e1t, eb1, e2t, eb2, e3t, eb3, (float*)d_out);
}

// Round 6
// 1172.333 us; speedup vs baseline: 16.6496x; 1.6952x over previous
//
#include <hip/hip_runtime.h>
#include <math.h>

typedef unsigned int uint;

// Dims
constexpr int BB  = 128;
constexpr int TT  = 512;
constexpr int DIN = 88;
constexpr int DZ  = 80;
constexpr int DH  = 400;
constexpr int DE  = 100;
constexpr int DTR = 200;
constexpr int DOUT = DIN + DZ + DZ; // 248

typedef __attribute__((ext_vector_type(8))) short bf16x8;
typedef __attribute__((ext_vector_type(4))) float f32x4;
union FU { uint4 u; bf16x8 v; };

__device__ __forceinline__ float softplusf(float x) {
    return fmaxf(x, 0.f) + log1pf(__expf(-fabsf(x)));
}
__device__ __forceinline__ float sigmoidf(float x) {
    return 1.f / (1.f + __expf(-x));
}
__device__ __forceinline__ uint bf16rn(float f) {
    uint u = __float_as_uint(f);
    return (u + 0x7FFFu + ((u >> 16) & 1u)) >> 16;
}
__device__ __forceinline__ uint pk2(float lo, float hi) {
    return bf16rn(lo) | (bf16rn(hi) << 16);
}
#define DOT2(ACC, Wv, Hv) asm("v_dot2_f32_bf16 %0, %1, %2, %0" : "+v"(ACC) : "v"(Wv), "v"(Hv))

__device__ __forceinline__ bf16x8 fragF32(const float* p) {
    float4 f0 = *(const float4*)p, f1 = *(const float4*)(p + 4);
    FU fu;
    fu.u.x = pk2(f0.x, f0.y); fu.u.y = pk2(f0.z, f0.w);
    fu.u.z = pk2(f1.x, f1.y); fu.u.w = pk2(f1.z, f1.w);
    return fu.v;
}
__device__ __forceinline__ bf16x8 fragF32relu(const float* p) {
    float4 f0 = *(const float4*)p, f1 = *(const float4*)(p + 4);
    FU fu;
    fu.u.x = pk2(fmaxf(f0.x, 0.f), fmaxf(f0.y, 0.f));
    fu.u.y = pk2(fmaxf(f0.z, 0.f), fmaxf(f0.w, 0.f));
    fu.u.z = pk2(fmaxf(f1.x, 0.f), fmaxf(f1.y, 0.f));
    fu.u.w = pk2(fmaxf(f1.z, 0.f), fmaxf(f1.w, 0.f));
    return fu.v;
}
#define MFMA(A, B, C) __builtin_amdgcn_mfma_f32_16x16x32_bf16((A), (B), (C), 0, 0, 0)

// ---------------- weight pack kernels ----------------

// Pack W [O][K] row-major into MFMA B-frag tiles (bf16, zero-padded).
// tile(nt,ks): lane l, dword d: k = ks*32+(l>>4)*8+2d, col o = nt*16+(l&15).
__global__ void packb_kernel(const float* __restrict__ W, uint* __restrict__ dst,
                             int O, int K, int KS, int tileOff) {
    int tile = blockIdx.x, r = threadIdx.x;
    int l = r >> 2, d = r & 3;
    int nt = tile / KS, ks = tile % KS;
    int o = nt * 16 + (l & 15);
    int k = ks * 32 + ((l >> 4) << 3) + 2 * d;
    uint lo = 0, hi = 0;
    if (o < O && k < K)     lo = bf16rn(W[o * K + k]);
    if (o < O && k + 1 < K) hi = bf16rn(W[o * K + k + 1]);
    dst[(size_t)(tileOff + tile) * 256 + r] = lo | (hi << 16);
}

// Pack W_hh into per-thread bf16-pair dwords for the rnn kernel (round-5 layout).
__global__ void pack_rnn(const float* __restrict__ W_hh, uint* __restrict__ Wb) {
    int idx = blockIdx.x * 256 + threadIdx.x;
    if (idx >= 200 * 512) return;
    int t = idx & 511, j = idx >> 9;
    uint val = 0u;
    int p = -1, hf = 0;
    if (t < 200) { p = t; hf = 0; }
    else if (t >= 256 && t < 456) { p = t - 256; hf = 1; }
    if (p >= 0) {
        int r  = 2 * p + (j >= 100 ? 1 : 0);
        int kd = hf * 100 + (j % 100);
        val = pk2(W_hh[r * DH + 2 * kd], W_hh[r * DH + 2 * kd + 1]);
    }
    Wb[(j >> 2) * 2048 + t * 4 + (j & 3)] = val;
}

// ---------------- pre GEMM (MFMA) ----------------
// pre[b][tt][h] = x[b][T-1-tt] @ W_ih^T + b_ih + b_hh.  N=400 (25 tiles), K=96 (3 steps).
__global__ __launch_bounds__(256) void pre_kernel(
    const float* __restrict__ x, const uint* __restrict__ bt,
    const float* __restrict__ b_ih, const float* __restrict__ b_hh,
    float* __restrict__ pre) {
    __shared__ float xs[16 * 100];
    const int b = blockIdx.y, tt0 = blockIdx.x * 16, tid = threadIdx.x;
    const int l = tid & 63, wid = tid >> 6, lr = l & 15, lg = l >> 4;
    for (int idx = tid; idx < 1600; idx += 256) {
        int r = idx / 100, k = idx % 100;
        xs[idx] = (k < DIN) ? x[((size_t)b * TT + (TT - 1 - (tt0 + r))) * DIN + k] : 0.f;
    }
    __syncthreads();
    bf16x8 af[3];
    #pragma unroll
    for (int ks = 0; ks < 3; ++ks) af[ks] = fragF32(xs + lr * 100 + ks * 32 + lg * 8);
    const uint4* bt4 = (const uint4*)bt;
    for (int nt = wid; nt < 25; nt += 4) {
        f32x4 acc = {0.f, 0.f, 0.f, 0.f};
        const uint4* bp = bt4 + (size_t)(388 + nt * 3) * 64 + l;
        #pragma unroll
        for (int ks = 0; ks < 3; ++ks) { FU bu; bu.u = bp[ks * 64]; acc = MFMA(af[ks], bu.v, acc); }
        int col = nt * 16 + lr;
        float bias = b_ih[col] + b_hh[col];
        #pragma unroll
        for (int i = 0; i < 4; ++i)
            pre[((size_t)b * TT + tt0 + lg * 4 + i) * DH + col] = acc[i] + bias;
    }
}

// ---------------- serial RNN scan (unchanged from round 5) ----------------
#define DLOOP(OFF)                                                              \
    _Pragma("unroll")                                                           \
    for (int d = 0; d < 100; ++d) {                                             \
        const int kd = (OFF) + d;                                               \
        const int hsrc = ((kd >> 6) == 0) ? hl0 : ((kd >> 6) == 1) ? hl1        \
                        : ((kd >> 6) == 2) ? hl2 : hl3;                         \
        int hv = __builtin_amdgcn_readlane(hsrc, kd & 63);                      \
        if (d & 1) { DOT2(r0b, W[d], hv); DOT2(r1b, W[100 + d], hv); }          \
        else       { DOT2(r0a, W[d], hv); DOT2(r1a, W[100 + d], hv); }          \
    }

__global__ __launch_bounds__(512) __attribute__((amdgpu_waves_per_eu(2, 2)))
void rnn_kernel(const uint* __restrict__ Wb, const float* __restrict__ h0,
                float* hs) {
    __shared__ uint h_lds[256];
    __shared__ float2 part[200];

    const int tid = threadIdx.x;
    const int lane = tid & 63;
    const bool a0 = (tid < 200);
    const bool a1 = (tid >= 256) && (tid < 456);
    const int p = a0 ? tid : (a1 ? tid - 256 : 0);

    uint W[200];
    const uint4* Wb4 = (const uint4*)Wb;
    #pragma unroll
    for (int j4 = 0; j4 < 50; ++j4) {
        uint4 v = Wb4[j4 * 512 + tid];
        W[4 * j4 + 0] = v.x; W[4 * j4 + 1] = v.y;
        W[4 * j4 + 2] = v.z; W[4 * j4 + 3] = v.w;
    }
    #pragma unroll
    for (int j = 0; j < 200; ++j) asm volatile("" : "+v"(W[j]));

    if (tid < 256)
        h_lds[tid] = (tid < 200) ? pk2(h0[2 * tid], h0[2 * tid + 1]) : 0u;
    __syncthreads();

    float* base = hs + (size_t)blockIdx.x * TT * DH;
    float2 pcur = make_float2(0.f, 0.f);
    if (a0) pcur = *(const float2*)(base + 2 * p);

    for (int tt = 0; tt < TT; ++tt) {
        int hl0 = (int)h_lds[lane];
        int hl1 = (int)h_lds[64 + lane];
        int hl2 = (int)h_lds[128 + lane];
        int hl3 = (int)h_lds[192 + lane];

        float2 pnxt = make_float2(0.f, 0.f);
        if (a0 && tt + 1 < TT) pnxt = *(const float2*)(base + (size_t)(tt + 1) * DH + 2 * p);

        float r0a = 0.f, r0b = 0.f, r1a = 0.f, r1b = 0.f;
        if (a0)      { DLOOP(0) }
        else if (a1) { DLOOP(100) }

        if (a1) part[p] = make_float2(r0a + r0b, r1a + r1b);
        __syncthreads();
        if (a0) {
            float2 q = part[p];
            float v0 = fmaxf(pcur.x + r0a + r0b + q.x, 0.f);
            float v1 = fmaxf(pcur.y + r1a + r1b + q.y, 0.f);
            uint pkd = pk2(v0, v1);
            h_lds[p] = pkd;
            ((uint*)(base + (size_t)tt * DH))[p] = pkd;
            pcur = pnxt;
        }
        __syncthreads();
    }
}

// ---------------- fused downstream (MFMA) ----------------
// Tile offsets in bt: P1 zloc 0 / zscale 65; P2 gW1 130 / pW1 169;
// P3 gW2 208 / pW2 243; P4 lW 278 / sW 293; P5 eW1 308; P6 eW2 332; P7 eW3 364.
__global__ __launch_bounds__(256) void e_kernel(
    const uint4* __restrict__ hs4, const float* __restrict__ eps,
    const float* __restrict__ z0, const uint* __restrict__ bt,
    const float* __restrict__ b_loc, const float* __restrict__ b_scale,
    const float* __restrict__ gb1, const float* __restrict__ pb1,
    const float* __restrict__ gb2, const float* __restrict__ pb2,
    const float* __restrict__ lb,  const float* __restrict__ sb,
    const float* __restrict__ eb1, const float* __restrict__ eb2,
    const float* __restrict__ eb3, float* __restrict__ out) {
    __shared__ float lds[12196];
    float* zl = lds;              // [17][100] fp32, cols 80-99 zero
    float* AP = lds + 1700;       // A:[16][228] | P at +3648; zpre overlays (stride 164)
    float* gp = lds + 8996;       // gate [16][100] | prop at +1600

    const int tid = threadIdx.x, l = tid & 63, wid = tid >> 6;
    const int b = blockIdx.y, t0 = blockIdx.x * 16;
    const int lr = l & 15, lg = l >> 4;
    const uint4* bt4 = (const uint4*)bt;

    bf16x8 zf[3];   // z_shift frags (rows 0..15), built in P2, reused in P4

    // ---- P1: zpre = hs_rows @ [W_loc|W_scale]^T  (2 M-tiles, N=160, K=416) ----
    {
        const int m0 = (wid >> 1) * 16;
        int r = m0 + lr;
        int t = t0 - 1 + r; t = min(max(t, 0), TT - 1);
        const uint4* rp = hs4 + ((size_t)b * TT + (TT - 1 - t)) * 100;
        bf16x8 af[13];
        FU zz; zz.u = make_uint4(0u, 0u, 0u, 0u);
        #pragma unroll
        for (int ks = 0; ks < 13; ++ks) {
            if (ks == 12 && lg >= 2) af[ks] = zz.v;      // k>=400 pad
            else { FU fu; fu.u = rp[ks * 4 + lg]; af[ks] = fu.v; }
        }
        for (int nt = (wid & 1); nt < 10; nt += 2) {
            f32x4 acc = {0.f, 0.f, 0.f, 0.f};
            const uint4* bp = bt4 + (size_t)(nt * 13) * 64 + l;
            #pragma unroll
            for (int ks = 0; ks < 13; ++ks) { FU bu; bu.u = bp[ks * 64]; acc = MFMA(af[ks], bu.v, acc); }
            int col = nt * 16 + lr;
            float bias = (col < DZ) ? b_loc[col] : b_scale[col - DZ];
            #pragma unroll
            for (int i = 0; i < 4; ++i) {
                int rr = m0 + lg * 4 + i;
                if (rr < 17) AP[rr * 164 + col] = acc[i] + bias;
            }
        }
    }
    __syncthreads();

    // ---- P1b: z = zloc + softplus(zscale)*eps (row0 at t0==0 -> z0); zl cols 80-99 = 0 ----
    for (int idx = tid; idx < 17 * 100; idx += 256) {
        int r = idx / 100, o = idx % 100;
        float zv = 0.f;
        if (o < DZ) {
            int t = t0 - 1 + r;
            if (t < 0) zv = z0[o];
            else {
                float sp = softplusf(AP[r * 164 + DZ + o]);
                zv = AP[r * 164 + o] + sp * eps[((size_t)b * TT + t) * DZ + o];
            }
        }
        zl[idx] = zv;
    }
    __syncthreads();

    // ---- P2: A/P = relu(z_shift @ {gW1,pW1}^T)  (26 tiles, K=96) ----
    {
        #pragma unroll
        for (int ks = 0; ks < 3; ++ks) zf[ks] = fragF32(zl + lr * 100 + ks * 32 + lg * 8);
        for (int idx = tid; idx < 640; idx += 256) {          // zero AP pad cols 208-227
            int h = idx / 320, rem = idx % 320;
            AP[h * 3648 + (rem / 20) * 228 + 208 + rem % 20] = 0.f;
        }
        for (int nt = wid; nt < 26; nt += 4) {
            f32x4 acc = {0.f, 0.f, 0.f, 0.f};
            const uint4* bp = bt4 + (size_t)(130 + nt * 3) * 64 + l;
            #pragma unroll
            for (int ks = 0; ks < 3; ++ks) { FU bu; bu.u = bp[ks * 64]; acc = MFMA(zf[ks], bu.v, acc); }
            int isP = nt >= 13;
            int col = (isP ? nt - 13 : nt) * 16 + lr;
            float bias = (col < DTR) ? (isP ? pb1[col] : gb1[col]) : 0.f;
            float* dst = AP + isP * 3648;
            #pragma unroll
            for (int i = 0; i < 4; ++i)
                dst[(lg * 4 + i) * 228 + col] = fmaxf(acc[i] + bias, 0.f);
        }
    }
    __syncthreads();

    // ---- P3: gate = sigmoid(A@gW2^T), prop = P@pW2^T  (K=224) ----
    {
        int half = wid >> 1;                  // 0: gate from A, 1: prop from P
        const float* src = AP + half * 3648;
        bf16x8 apf[7];
        #pragma unroll
        for (int ks = 0; ks < 7; ++ks) apf[ks] = fragF32(src + lr * 228 + ks * 32 + lg * 8);
        for (int idx = tid; idx < 640; idx += 256) {          // zero gp cols 80-99
            int h = idx / 320, rem = idx % 320;
            gp[h * 1600 + (rem / 20) * 100 + 80 + rem % 20] = 0.f;
        }
        for (int nt = (wid & 1); nt < 5; nt += 2) {
            f32x4 acc = {0.f, 0.f, 0.f, 0.f};
            const uint4* bp = bt4 + (size_t)(208 + half * 35 + nt * 7) * 64 + l;
            #pragma unroll
            for (int ks = 0; ks < 7; ++ks) { FU bu; bu.u = bp[ks * 64]; acc = MFMA(apf[ks], bu.v, acc); }
            int col = nt * 16 + lr;
            float bias = half ? pb2[col] : gb2[col];
            float* dst = gp + half * 1600;
            #pragma unroll
            for (int i = 0; i < 4; ++i) {
                float v = acc[i] + bias;
                dst[(lg * 4 + i) * 100 + col] = half ? v : sigmoidf(v);
            }
        }
    }
    __syncthreads();

    // ---- P4 (trans_loc/trans_scale -> global) + P5 (h1 = relu(z@eW1^T)) ----
    {
        bf16x8 z1f[3], prf[3];
        #pragma unroll
        for (int ks = 0; ks < 3; ++ks) {
            z1f[ks] = fragF32(zl + (1 + lr) * 100 + ks * 32 + lg * 8);
            prf[ks] = fragF32relu(gp + 1600 + lr * 100 + ks * 32 + lg * 8);
        }
        for (int tsk = wid; tsk < 18; tsk += 4) {
            if (tsk < 5) {              // trans_loc: (1-g)*(z@lW^T+lb) + g*prop
                f32x4 acc = {0.f, 0.f, 0.f, 0.f};
                const uint4* bp = bt4 + (size_t)(278 + tsk * 3) * 64 + l;
                #pragma unroll
                for (int ks = 0; ks < 3; ++ks) { FU bu; bu.u = bp[ks * 64]; acc = MFMA(zf[ks], bu.v, acc); }
                int col = tsk * 16 + lr;
                float bias = lb[col];
                #pragma unroll
                for (int i = 0; i < 4; ++i) {
                    int rr = lg * 4 + i;
                    float g  = gp[rr * 100 + col];
                    float pv = gp[1600 + rr * 100 + col];
                    out[((size_t)b * TT + t0 + rr) * DOUT + DIN + col] =
                        (1.f - g) * (acc[i] + bias) + g * pv;
                }
            } else if (tsk < 10) {      // trans_scale = softplus(relu(prop)@sW^T+sb)
                int nt = tsk - 5;
                f32x4 acc = {0.f, 0.f, 0.f, 0.f};
                const uint4* bp = bt4 + (size_t)(293 + nt * 3) * 64 + l;
                #pragma unroll
                for (int ks = 0; ks < 3; ++ks) { FU bu; bu.u = bp[ks * 64]; acc = MFMA(prf[ks], bu.v, acc); }
                int col = nt * 16 + lr;
                float bias = sb[col];
                #pragma unroll
                for (int i = 0; i < 4; ++i)
                    out[((size_t)b * TT + t0 + lg * 4 + i) * DOUT + DIN + DZ + col] =
                        softplusf(acc[i] + bias);
            } else {                    // h1 tiles (N=128 pad)
                int nt = tsk - 10;
                f32x4 acc = {0.f, 0.f, 0.f, 0.f};
                const uint4* bp = bt4 + (size_t)(308 + nt * 3) * 64 + l;
                #pragma unroll
                for (int ks = 0; ks < 3; ++ks) { FU bu; bu.u = bp[ks * 64]; acc = MFMA(z1f[ks], bu.v, acc); }
                int col = nt * 16 + lr;
                float bias = (col < DE) ? eb1[col] : 0.f;
                #pragma unroll
                for (int i = 0; i < 4; ++i)
                    AP[(lg * 4 + i) * 228 + col] = fmaxf(acc[i] + bias, 0.f);
            }
        }
    }
    __syncthreads();

    // ---- P6: h2 = relu(h1 @ eW2^T)  (K=128, N=128 pad) ----
    {
        bf16x8 hf[4];
        #pragma unroll
        for (int ks = 0; ks < 4; ++ks) hf[ks] = fragF32(AP + lr * 228 + ks * 32 + lg * 8);
        for (int nt = wid; nt < 8; nt += 4) {
            f32x4 acc = {0.f, 0.f, 0.f, 0.f};
            const uint4* bp = bt4 + (size_t)(332 + nt * 4) * 64 + l;
            #pragma unroll
            for (int ks = 0; ks < 4; ++ks) { FU bu; bu.u = bp[ks * 64]; acc = MFMA(hf[ks], bu.v, acc); }
            int col = nt * 16 + lr;
            float bias = (col < DE) ? eb2[col] : 0.f;
            #pragma unroll
            for (int i = 0; i < 4; ++i)
                AP[3648 + (lg * 4 + i) * 228 + col] = fmaxf(acc[i] + bias, 0.f);
        }
    }
    __syncthreads();

    // ---- P7: emis = sigmoid(h2 @ eW3^T) -> out[0..88) ----
    {
        bf16x8 hf[4];
        #pragma unroll
        for (int ks = 0; ks < 4; ++ks) hf[ks] = fragF32(AP + 3648 + lr * 228 + ks * 32 + lg * 8);
        for (int nt = wid; nt < 6; nt += 4) {
            f32x4 acc = {0.f, 0.f, 0.f, 0.f};
            const uint4* bp = bt4 + (size_t)(364 + nt * 4) * 64 + l;
            #pragma unroll
            for (int ks = 0; ks < 4; ++ks) { FU bu; bu.u = bp[ks * 64]; acc = MFMA(hf[ks], bu.v, acc); }
            int col = nt * 16 + lr;
            if (col < DIN) {
                float bias = eb3[col];
                #pragma unroll
                for (int i = 0; i < 4; ++i)
                    out[((size_t)b * TT + t0 + lg * 4 + i) * DOUT + col] = sigmoidf(acc[i] + bias);
            }
        }
    }
}

extern "C" void kernel_launch(void* const* d_in, const int* in_sizes, int n_in,
                              void* d_out, int out_size, void* d_ws, size_t ws_size,
                              hipStream_t stream) {
    const float* x       = (const float*)d_in[0];
    const float* eps     = (const float*)d_in[1];
    const float* W_ih    = (const float*)d_in[2];
    const float* W_hh    = (const float*)d_in[3];
    const float* b_ih    = (const float*)d_in[4];
    const float* b_hh    = (const float*)d_in[5];
    const float* h0      = (const float*)d_in[6];
    const float* z0      = (const float*)d_in[7];
    const float* W_loc   = (const float*)d_in[8];
    const float* b_loc   = (const float*)d_in[9];
    const float* W_scale = (const float*)d_in[10];
    const float* b_scale = (const float*)d_in[11];
    const float* gW1 = (const float*)d_in[12];
    const float* gb1 = (const float*)d_in[13];
    const float* gW2 = (const float*)d_in[14];
    const float* gb2 = (const float*)d_in[15];
    const float* pW1 = (const float*)d_in[16];
    const float* pb1 = (const float*)d_in[17];
    const float* pW2 = (const float*)d_in[18];
    const float* pb2 = (const float*)d_in[19];
    const float* sW  = (const float*)d_in[20];
    const float* sb  = (const float*)d_in[21];
    const float* lW  = (const float*)d_in[22];
    const float* lb  = (const float*)d_in[23];
    const float* eW1 = (const float*)d_in[24];
    const float* eb1 = (const float*)d_in[25];
    const float* eW2 = (const float*)d_in[26];
    const float* eb2 = (const float*)d_in[27];
    const float* eW3 = (const float*)d_in[28];
    const float* eb3 = (const float*)d_in[29];

    float* wsf = (float*)d_ws;
    float* prebuf = wsf;                               // B*T*DH floats (pre -> hs bf16)
    uint*  Wb = (uint*)(wsf + (size_t)BB * TT * DH);   // 102400 dwords (rnn W)
    uint*  bt = Wb + 102400;                           // 463 tiles * 256 dwords

    pack_rnn<<<400, 256, 0, stream>>>(W_hh, Wb);
    // B-frag tile packs: (W, O, K, KS, tileOff), grid = NT*KS
    packb_kernel<<<5 * 13, 256, 0, stream>>>(W_loc,   bt,  DZ, DH, 13, 0);
    packb_kernel<<<5 * 13, 256, 0, stream>>>(W_scale, bt,  DZ, DH, 13, 65);
    packb_kernel<<<13 * 3, 256, 0, stream>>>(gW1,     bt, DTR, DZ,  3, 130);
    packb_kernel<<<13 * 3, 256, 0, stream>>>(pW1,     bt, DTR, DZ,  3, 169);
    packb_kernel<<<5 * 7,  256, 0, stream>>>(gW2,     bt,  DZ, DTR, 7, 208);
    packb_kernel<<<5 * 7,  256, 0, stream>>>(pW2,     bt,  DZ, DTR, 7, 243);
    packb_kernel<<<5 * 3,  256, 0, stream>>>(lW,      bt,  DZ, DZ,  3, 278);
    packb_kernel<<<5 * 3,  256, 0, stream>>>(sW,      bt,  DZ, DZ,  3, 293);
    packb_kernel<<<8 * 3,  256, 0, stream>>>(eW1,     bt,  DE, DZ,  3, 308);
    packb_kernel<<<8 * 4,  256, 0, stream>>>(eW2,     bt,  DE, DE,  4, 332);
    packb_kernel<<<6 * 4,  256, 0, stream>>>(eW3,     bt, DIN, DE,  4, 364);
    packb_kernel<<<25 * 3, 256, 0, stream>>>(W_ih,    bt,  DH, DIN, 3, 388);

    pre_kernel<<<dim3(TT / 16, BB), 256, 0, stream>>>(x, bt, b_ih, b_hh, prebuf);
    rnn_kernel<<<dim3(BB), dim3(512), 0, stream>>>(Wb, h0, prebuf);
    e_kernel<<<dim3(TT / 16, BB), 256, 0, stream>>>(
        (const uint4*)prebuf, eps, z0, bt,
        b_loc, b_scale, gb1, pb1, gb2, pb2, lb, sb, eb1, eb2, eb3,
        (float*)d_out);
}

// Round 7
// 1130.273 us; speedup vs baseline: 17.2691x; 1.0372x over previous
//
#include <hip/hip_runtime.h>
#include <math.h>

typedef unsigned int uint;

// Dims
constexpr int BB  = 128;
constexpr int TT  = 512;
constexpr int DIN = 88;
constexpr int DZ  = 80;
constexpr int DH  = 400;
constexpr int DE  = 100;
constexpr int DTR = 200;
constexpr int DOUT = DIN + DZ + DZ; // 248

typedef __attribute__((ext_vector_type(8))) short bf16x8;
typedef __attribute__((ext_vector_type(4))) float f32x4;
typedef __attribute__((ext_vector_type(4))) uint  u32x4;
union FU { u32x4 u; bf16x8 v; };

__device__ __forceinline__ float softplusf(float x) {
    return fmaxf(x, 0.f) + log1pf(__expf(-fabsf(x)));
}
__device__ __forceinline__ float sigmoidf(float x) {
    return 1.f / (1.f + __expf(-x));
}
__device__ __forceinline__ uint bf16rn(float f) {
    uint u = __float_as_uint(f);
    return (u + 0x7FFFu + ((u >> 16) & 1u)) >> 16;
}
__device__ __forceinline__ uint pk2(float lo, float hi) {
    return bf16rn(lo) | (bf16rn(hi) << 16);
}
__device__ __forceinline__ bf16x8 fragF32(const float* p) {
    float4 f0 = *(const float4*)p, f1 = *(const float4*)(p + 4);
    FU fu;
    fu.u.x = pk2(f0.x, f0.y); fu.u.y = pk2(f0.z, f0.w);
    fu.u.z = pk2(f1.x, f1.y); fu.u.w = pk2(f1.z, f1.w);
    return fu.v;
}
__device__ __forceinline__ bf16x8 fragF32relu(const float* p) {
    float4 f0 = *(const float4*)p, f1 = *(const float4*)(p + 4);
    FU fu;
    fu.u.x = pk2(fmaxf(f0.x, 0.f), fmaxf(f0.y, 0.f));
    fu.u.y = pk2(fmaxf(f0.z, 0.f), fmaxf(f0.w, 0.f));
    fu.u.z = pk2(fmaxf(f1.x, 0.f), fmaxf(f1.y, 0.f));
    fu.u.w = pk2(fmaxf(f1.z, 0.f), fmaxf(f1.w, 0.f));
    return fu.v;
}
#define MFMA(A, B, C) __builtin_amdgcn_mfma_f32_16x16x32_bf16((A), (B), (C), 0, 0, 0)

// ---------------- fused weight pack ----------------
// All weights -> MFMA frag tiles (bf16, zero-padded). tile(nt,ks): lane l,
// dword d: k = ks*32+(l>>4)*8+2d, o = nt*16+(l&15). Same layout serves A or B.
struct Srcs { const float* p[13]; };

__global__ __launch_bounds__(256) void packall_kernel(Srcs s, uint* __restrict__ dst) {
    constexpr int O_[13]   = {80,80,200,200,80,80,80,80,100,100,88,400,400};
    constexpr int K_[13]   = {400,400,80,80,200,200,80,80,80,100,100,88,400};
    constexpr int KS_[13]  = {13,13,3,3,7,7,3,3,3,4,4,3,13};
    constexpr int OFF_[13] = {0,65,130,169,208,243,278,293,308,332,364,388,463};
    int tile = blockIdx.x;
    int e = 0;
    #pragma unroll
    for (int i = 1; i < 13; ++i) if (tile >= OFF_[i]) e = i;
    int lt = tile - OFF_[e];
    int nt = lt / KS_[e], ks = lt % KS_[e];
    const float* W = s.p[e];
    int r = threadIdx.x, l = r >> 2, d = r & 3;
    int o = nt * 16 + (l & 15);
    int k = ks * 32 + ((l >> 4) << 3) + 2 * d;
    uint lo = 0, hi = 0;
    if (o < O_[e] && k < K_[e])     lo = bf16rn(W[o * K_[e] + k]);
    if (o < O_[e] && k + 1 < K_[e]) hi = bf16rn(W[o * K_[e] + k + 1]);
    dst[(size_t)tile * 256 + r] = lo | (hi << 16);
}

constexpr int WHH = 463;   // W_hh tiles: (mt,ks) at WHH + mt*13 + ks; 25 M-tiles

// ---------------- pre GEMM (MFMA) ----------------
__global__ __launch_bounds__(256) void pre_kernel(
    const float* __restrict__ x, const uint* __restrict__ bt,
    const float* __restrict__ b_ih, const float* __restrict__ b_hh,
    float* __restrict__ pre) {
    __shared__ float xs[16 * 100];
    const int b = blockIdx.y, tt0 = blockIdx.x * 16, tid = threadIdx.x;
    const int l = tid & 63, wid = tid >> 6, lr = l & 15, lg = l >> 4;
    for (int idx = tid; idx < 1600; idx += 256) {
        int r = idx / 100, k = idx % 100;
        xs[idx] = (k < DIN) ? x[((size_t)b * TT + (TT - 1 - (tt0 + r))) * DIN + k] : 0.f;
    }
    __syncthreads();
    bf16x8 af[3];
    #pragma unroll
    for (int ks = 0; ks < 3; ++ks) af[ks] = fragF32(xs + lr * 100 + ks * 32 + lg * 8);
    const uint4* bt4 = (const uint4*)bt;
    for (int nt = wid; nt < 25; nt += 4) {
        f32x4 acc = {0.f, 0.f, 0.f, 0.f};
        const uint4* bp = bt4 + (size_t)(388 + nt * 3) * 64 + l;
        #pragma unroll
        for (int ks = 0; ks < 3; ++ks) { FU bu; bu.u = *(const u32x4*)(bp + ks * 64); acc = MFMA(af[ks], bu.v, acc); }
        int col = nt * 16 + lr;
        float bias = b_ih[col] + b_hh[col];
        #pragma unroll
        for (int i = 0; i < 4; ++i)
            pre[((size_t)b * TT + tt0 + lg * 4 + i) * DH + col] = acc[i] + bias;
    }
}

// ---------------- serial RNN scan (MFMA, 16 batches/block, 8 blocks) ----------------
// h_new^T[400][16] = W_hh @ h^T. A = W (static: 3 tiles/wave in regs, tile 24
// streamed from LDS by wave 7). B = h (packed bf16 in LDS, rebuilt per step).
// C: col=batch(l&15), row=h_idx -> relu+pack -> ds_write_b64 in B-layout (no transpose).
// pre staged 1 step ahead (reg path: load early, write late). 1 barrier/step.
__global__ __launch_bounds__(512) __attribute__((amdgpu_waves_per_eu(2, 2)))
void rnn_kernel(const u32x4* __restrict__ bt4, const float* __restrict__ h0,
                float* __restrict__ prehs) {
    extern __shared__ char smem[];
    uint*  hb   = (uint*)smem;                       // [2][16][212] packed bf16 h (dwords 200-211 zero pad)
    float* pb   = (float*)(smem + 27136);            // [2][16][404] staged pre (fp32)
    u32x4* wt24 = (u32x4*)(smem + 27136 + 51712);    // [13*64] tile-24 W frags

    const int tid = threadIdx.x, lane = tid & 63, wid = tid >> 6;
    const int batch = lane & 15, lg = lane >> 4;
    const int b0 = blockIdx.x * 16;

    // resident A (W) tiles: wave w owns mt = 3w, 3w+1, 3w+2
    u32x4 A0[13], A1[13], A2[13];
    {
        const u32x4* base = bt4 + (size_t)(WHH + 3 * wid * 13) * 64 + lane;
        #pragma unroll
        for (int ks = 0; ks < 13; ++ks) {
            A0[ks] = base[ks * 64];
            A1[ks] = base[(13 + ks) * 64];
            A2[ks] = base[(26 + ks) * 64];
        }
    }
    #pragma unroll
    for (int ks = 0; ks < 13; ++ks)
        asm volatile("" : "+v"(A0[ks]), "+v"(A1[ks]), "+v"(A2[ks]));

    // stage tile-24 W into LDS
    for (int i = tid; i < 13 * 64; i += 512)
        wt24[i] = bt4[(size_t)(WHH + 24 * 13) * 64 + i];

    // zero hb pad dwords (both buffers), fill h0 into buf0
    for (int i = tid; i < 2 * 16 * 12; i += 512) {
        int buf = i / 192, r = i % 192, bs = r / 12, d = 200 + r % 12;
        hb[buf * 3392 + bs * 212 + d] = 0u;
    }
    for (int i = tid; i < 16 * 200; i += 512) {
        int bs = i / 200, d = i % 200;
        hb[bs * 212 + d] = pk2(h0[2 * d], h0[2 * d + 1]);
    }
    // stage pre_0 (wave w -> batches 2w, 2w+1)
    {
        const u32x4* ra = (const u32x4*)(prehs + ((size_t)(b0 + 2 * wid) * TT) * DH);
        const u32x4* rb = (const u32x4*)(prehs + ((size_t)(b0 + 2 * wid + 1) * TT) * DH);
        u32x4* wa = (u32x4*)(pb + (2 * wid) * 404);
        u32x4* wb = (u32x4*)(pb + (2 * wid + 1) * 404);
        wa[lane] = ra[lane];
        wb[lane] = rb[lane];
        if (lane < 36) { wa[64 + lane] = ra[64 + lane]; wb[64 + lane] = rb[64 + lane]; }
    }
    __syncthreads();

    uint cur = 0;
    for (int tt = 0; tt < TT; ++tt) {
        // issue next-step pre loads early (latency hides under MFMA)
        u32x4 na0, na1, nb0, nb1;
        const bool hasNext = (tt + 1 < TT);
        if (hasNext) {
            const u32x4* ra = (const u32x4*)(prehs + ((size_t)(b0 + 2 * wid) * TT + tt + 1) * DH);
            const u32x4* rb = (const u32x4*)(prehs + ((size_t)(b0 + 2 * wid + 1) * TT + tt + 1) * DH);
            na0 = ra[lane]; nb0 = rb[lane];
            if (lane < 36) { na1 = ra[64 + lane]; nb1 = rb[64 + lane]; }
        }

        const uint*  hcur = hb + cur * 3392;
        const float* pcur = pb + cur * (16 * 404);
        f32x4 c0 = {0.f, 0.f, 0.f, 0.f}, c1 = c0, c2 = c0, c24 = c0;
        const u32x4* hrow = (const u32x4*)(hcur + batch * 212);
        #pragma unroll
        for (int ks = 0; ks < 13; ++ks) {
            FU b; b.u = hrow[ks * 4 + lg];
            FU a0; a0.u = A0[ks]; c0 = MFMA(a0.v, b.v, c0);
            FU a1; a1.u = A1[ks]; c1 = MFMA(a1.v, b.v, c1);
            FU a2; a2.u = A2[ks]; c2 = MFMA(a2.v, b.v, c2);
            if (wid == 7) { FU w; w.u = wt24[ks * 64 + lane]; c24 = MFMA(w.v, b.v, c24); }
        }

        uint*  hnxt = hb + (cur ^ 1) * 3392;
        float* pnxt = pb + (cur ^ 1) * (16 * 404);
        uint*  grow = (uint*)prehs + ((size_t)(b0 + batch) * TT + tt) * DH;

        #pragma unroll
        for (int s = 0; s < 3; ++s) {
            const int mt = 3 * wid + s;
            f32x4 c = (s == 0) ? c0 : (s == 1) ? c1 : c2;
            float4 pr = *(const float4*)(pcur + batch * 404 + mt * 16 + lg * 4);
            uint d0 = pk2(fmaxf(c[0] + pr.x, 0.f), fmaxf(c[1] + pr.y, 0.f));
            uint d1 = pk2(fmaxf(c[2] + pr.z, 0.f), fmaxf(c[3] + pr.w, 0.f));
            uint2 dd = make_uint2(d0, d1);
            *(uint2*)(hnxt + batch * 212 + mt * 8 + lg * 2) = dd;
            *(uint2*)(grow + mt * 8 + lg * 2) = dd;
        }
        if (wid == 7) {
            float4 pr = *(const float4*)(pcur + batch * 404 + 24 * 16 + lg * 4);
            uint d0 = pk2(fmaxf(c24[0] + pr.x, 0.f), fmaxf(c24[1] + pr.y, 0.f));
            uint d1 = pk2(fmaxf(c24[2] + pr.z, 0.f), fmaxf(c24[3] + pr.w, 0.f));
            uint2 dd = make_uint2(d0, d1);
            *(uint2*)(hnxt + batch * 212 + 24 * 8 + lg * 2) = dd;
            *(uint2*)(grow + 24 * 8 + lg * 2) = dd;
        }

        // write staged pre late
        if (hasNext) {
            u32x4* wa = (u32x4*)(pnxt + (2 * wid) * 404);
            u32x4* wb = (u32x4*)(pnxt + (2 * wid + 1) * 404);
            wa[lane] = na0; wb[lane] = nb0;
            if (lane < 36) { wa[64 + lane] = na1; wb[64 + lane] = nb1; }
        }
        __syncthreads();
        cur ^= 1;
    }
}

// ---------------- fused downstream (MFMA, unchanged from round 6) ----------------
__global__ __launch_bounds__(256) void e_kernel(
    const uint4* __restrict__ hs4, const float* __restrict__ eps,
    const float* __restrict__ z0, const uint* __restrict__ bt,
    const float* __restrict__ b_loc, const float* __restrict__ b_scale,
    const float* __restrict__ gb1, const float* __restrict__ pb1,
    const float* __restrict__ gb2, const float* __restrict__ pb2,
    const float* __restrict__ lb,  const float* __restrict__ sb,
    const float* __restrict__ eb1, const float* __restrict__ eb2,
    const float* __restrict__ eb3, float* __restrict__ out) {
    __shared__ float lds[12196];
    float* zl = lds;              // [17][100] fp32, cols 80-99 zero
    float* AP = lds + 1700;       // A:[16][228] | P at +3648; zpre overlays (stride 164)
    float* gp = lds + 8996;       // gate [16][100] | prop at +1600

    const int tid = threadIdx.x, l = tid & 63, wid = tid >> 6;
    const int b = blockIdx.y, t0 = blockIdx.x * 16;
    const int lr = l & 15, lg = l >> 4;
    const uint4* bt4 = (const uint4*)bt;

    bf16x8 zf[3];

    // ---- P1: zpre = hs_rows @ [W_loc|W_scale]^T ----
    {
        const int m0 = (wid >> 1) * 16;
        int r = m0 + lr;
        int t = t0 - 1 + r; t = min(max(t, 0), TT - 1);
        const uint4* rp = hs4 + ((size_t)b * TT + (TT - 1 - t)) * 100;
        bf16x8 af[13];
        FU zz; zz.u = (u32x4){0u, 0u, 0u, 0u};
        #pragma unroll
        for (int ks = 0; ks < 13; ++ks) {
            if (ks == 12 && lg >= 2) af[ks] = zz.v;
            else { FU fu; fu.u = *(const u32x4*)(rp + ks * 4 + lg); af[ks] = fu.v; }
        }
        for (int nt = (wid & 1); nt < 10; nt += 2) {
            f32x4 acc = {0.f, 0.f, 0.f, 0.f};
            const uint4* bp = bt4 + (size_t)(nt * 13) * 64 + l;
            #pragma unroll
            for (int ks = 0; ks < 13; ++ks) { FU bu; bu.u = *(const u32x4*)(bp + ks * 64); acc = MFMA(af[ks], bu.v, acc); }
            int col = nt * 16 + lr;
            float bias = (col < DZ) ? b_loc[col] : b_scale[col - DZ];
            #pragma unroll
            for (int i = 0; i < 4; ++i) {
                int rr = m0 + lg * 4 + i;
                if (rr < 17) AP[rr * 164 + col] = acc[i] + bias;
            }
        }
    }
    __syncthreads();

    // ---- P1b: z = zloc + softplus(zscale)*eps ----
    for (int idx = tid; idx < 17 * 100; idx += 256) {
        int r = idx / 100, o = idx % 100;
        float zv = 0.f;
        if (o < DZ) {
            int t = t0 - 1 + r;
            if (t < 0) zv = z0[o];
            else {
                float sp = softplusf(AP[r * 164 + DZ + o]);
                zv = AP[r * 164 + o] + sp * eps[((size_t)b * TT + t) * DZ + o];
            }
        }
        zl[idx] = zv;
    }
    __syncthreads();

    // ---- P2: A/P = relu(z_shift @ {gW1,pW1}^T) ----
    {
        #pragma unroll
        for (int ks = 0; ks < 3; ++ks) zf[ks] = fragF32(zl + lr * 100 + ks * 32 + lg * 8);
        for (int idx = tid; idx < 640; idx += 256) {
            int h = idx / 320, rem = idx % 320;
            AP[h * 3648 + (rem / 20) * 228 + 208 + rem % 20] = 0.f;
        }
        for (int nt = wid; nt < 26; nt += 4) {
            f32x4 acc = {0.f, 0.f, 0.f, 0.f};
            const uint4* bp = bt4 + (size_t)(130 + nt * 3) * 64 + l;
            #pragma unroll
            for (int ks = 0; ks < 3; ++ks) { FU bu; bu.u = *(const u32x4*)(bp + ks * 64); acc = MFMA(zf[ks], bu.v, acc); }
            int isP = nt >= 13;
            int col = (isP ? nt - 13 : nt) * 16 + lr;
            float bias = (col < DTR) ? (isP ? pb1[col] : gb1[col]) : 0.f;
            float* dst = AP + isP * 3648;
            #pragma unroll
            for (int i = 0; i < 4; ++i)
                dst[(lg * 4 + i) * 228 + col] = fmaxf(acc[i] + bias, 0.f);
        }
    }
    __syncthreads();

    // ---- P3: gate = sigmoid(A@gW2^T), prop = P@pW2^T ----
    {
        int half = wid >> 1;
        const float* src = AP + half * 3648;
        bf16x8 apf[7];
        #pragma unroll
        for (int ks = 0; ks < 7; ++ks) apf[ks] = fragF32(src + lr * 228 + ks * 32 + lg * 8);
        for (int idx = tid; idx < 640; idx += 256) {
            int h = idx / 320, rem = idx % 320;
            gp[h * 1600 + (rem / 20) * 100 + 80 + rem % 20] = 0.f;
        }
        for (int nt = (wid & 1); nt < 5; nt += 2) {
            f32x4 acc = {0.f, 0.f, 0.f, 0.f};
            const uint4* bp = bt4 + (size_t)(208 + half * 35 + nt * 7) * 64 + l;
            #pragma unroll
            for (int ks = 0; ks < 7; ++ks) { FU bu; bu.u = *(const u32x4*)(bp + ks * 64); acc = MFMA(apf[ks], bu.v, acc); }
            int col = nt * 16 + lr;
            float bias = half ? pb2[col] : gb2[col];
            float* dst = gp + half * 1600;
            #pragma unroll
            for (int i = 0; i < 4; ++i) {
                float v = acc[i] + bias;
                dst[(lg * 4 + i) * 100 + col] = half ? v : sigmoidf(v);
            }
        }
    }
    __syncthreads();

    // ---- P4 (trans_loc/trans_scale) + P5 (h1) ----
    {
        bf16x8 z1f[3], prf[3];
        #pragma unroll
        for (int ks = 0; ks < 3; ++ks) {
            z1f[ks] = fragF32(zl + (1 + lr) * 100 + ks * 32 + lg * 8);
            prf[ks] = fragF32relu(gp + 1600 + lr * 100 + ks * 32 + lg * 8);
        }
        for (int tsk = wid; tsk < 18; tsk += 4) {
            if (tsk < 5) {
                f32x4 acc = {0.f, 0.f, 0.f, 0.f};
                const uint4* bp = bt4 + (size_t)(278 + tsk * 3) * 64 + l;
                #pragma unroll
                for (int ks = 0; ks < 3; ++ks) { FU bu; bu.u = *(const u32x4*)(bp + ks * 64); acc = MFMA(zf[ks], bu.v, acc); }
                int col = tsk * 16 + lr;
                float bias = lb[col];
                #pragma unroll
                for (int i = 0; i < 4; ++i) {
                    int rr = lg * 4 + i;
                    float g  = gp[rr * 100 + col];
                    float pv = gp[1600 + rr * 100 + col];
                    out[((size_t)b * TT + t0 + rr) * DOUT + DIN + col] =
                        (1.f - g) * (acc[i] + bias) + g * pv;
                }
            } else if (tsk < 10) {
                int nt = tsk - 5;
                f32x4 acc = {0.f, 0.f, 0.f, 0.f};
                const uint4* bp = bt4 + (size_t)(293 + nt * 3) * 64 + l;
                #pragma unroll
                for (int ks = 0; ks < 3; ++ks) { FU bu; bu.u = *(const u32x4*)(bp + ks * 64); acc = MFMA(prf[ks], bu.v, acc); }
                int col = nt * 16 + lr;
                float bias = sb[col];
                #pragma unroll
                for (int i = 0; i < 4; ++i)
                    out[((size_t)b * TT + t0 + lg * 4 + i) * DOUT + DIN + DZ + col] =
                        softplusf(acc[i] + bias);
            } else {
                int nt = tsk - 10;
                f32x4 acc = {0.f, 0.f, 0.f, 0.f};
                const uint4* bp = bt4 + (size_t)(308 + nt * 3) * 64 + l;
                #pragma unroll
                for (int ks = 0; ks < 3; ++ks) { FU bu; bu.u = *(const u32x4*)(bp + ks * 64); acc = MFMA(z1f[ks], bu.v, acc); }
                int col = nt * 16 + lr;
                float bias = (col < DE) ? eb1[col] : 0.f;
                #pragma unroll
                for (int i = 0; i < 4; ++i)
                    AP[(lg * 4 + i) * 228 + col] = fmaxf(acc[i] + bias, 0.f);
            }
        }
    }
    __syncthreads();

    // ---- P6: h2 = relu(h1 @ eW2^T) ----
    {
        bf16x8 hf[4];
        #pragma unroll
        for (int ks = 0; ks < 4; ++ks) hf[ks] = fragF32(AP + lr * 228 + ks * 32 + lg * 8);
        for (int nt = wid; nt < 8; nt += 4) {
            f32x4 acc = {0.f, 0.f, 0.f, 0.f};
            const uint4* bp = bt4 + (size_t)(332 + nt * 4) * 64 + l;
            #pragma unroll
            for (int ks = 0; ks < 4; ++ks) { FU bu; bu.u = *(const u32x4*)(bp + ks * 64); acc = MFMA(hf[ks], bu.v, acc); }
            int col = nt * 16 + lr;
            float bias = (col < DE) ? eb2[col] : 0.f;
            #pragma unroll
            for (int i = 0; i < 4; ++i)
                AP[3648 + (lg * 4 + i) * 228 + col] = fmaxf(acc[i] + bias, 0.f);
        }
    }
    __syncthreads();

    // ---- P7: emis = sigmoid(h2 @ eW3^T) ----
    {
        bf16x8 hf[4];
        #pragma unroll
        for (int ks = 0; ks < 4; ++ks) hf[ks] = fragF32(AP + 3648 + lr * 228 + ks * 32 + lg * 8);
        for (int nt = wid; nt < 6; nt += 4) {
            f32x4 acc = {0.f, 0.f, 0.f, 0.f};
            const uint4* bp = bt4 + (size_t)(364 + nt * 4) * 64 + l;
            #pragma unroll
            for (int ks = 0; ks < 4; ++ks) { FU bu; bu.u = *(const u32x4*)(bp + ks * 64); acc = MFMA(hf[ks], bu.v, acc); }
            int col = nt * 16 + lr;
            if (col < DIN) {
                float bias = eb3[col];
                #pragma unroll
                for (int i = 0; i < 4; ++i)
                    out[((size_t)b * TT + t0 + lg * 4 + i) * DOUT + col] = sigmoidf(acc[i] + bias);
            }
        }
    }
}

extern "C" void kernel_launch(void* const* d_in, const int* in_sizes, int n_in,
                              void* d_out, int out_size, void* d_ws, size_t ws_size,
                              hipStream_t stream) {
    const float* x       = (const float*)d_in[0];
    const float* eps     = (const float*)d_in[1];
    const float* W_ih    = (const float*)d_in[2];
    const float* W_hh    = (const float*)d_in[3];
    const float* b_ih    = (const float*)d_in[4];
    const float* b_hh    = (const float*)d_in[5];
    const float* h0      = (const float*)d_in[6];
    const float* z0      = (const float*)d_in[7];
    const float* W_loc   = (const float*)d_in[8];
    const float* b_loc   = (const float*)d_in[9];
    const float* W_scale = (const float*)d_in[10];
    const float* b_scale = (const float*)d_in[11];
    const float* gW1 = (const float*)d_in[12];
    const float* gb1 = (const float*)d_in[13];
    const float* gW2 = (const float*)d_in[14];
    const float* gb2 = (const float*)d_in[15];
    const float* pW1 = (const float*)d_in[16];
    const float* pb1 = (const float*)d_in[17];
    const float* pW2 = (const float*)d_in[18];
    const float* pb2 = (const float*)d_in[19];
    const float* sW  = (const float*)d_in[20];
    const float* sb  = (const float*)d_in[21];
    const float* lW  = (const float*)d_in[22];
    const float* lb  = (const float*)d_in[23];
    const float* eW1 = (const float*)d_in[24];
    const float* eb1 = (const float*)d_in[25];
    const float* eW2 = (const float*)d_in[26];
    const float* eb2 = (const float*)d_in[27];
    const float* eW3 = (const float*)d_in[28];
    const float* eb3 = (const float*)d_in[29];

    float* wsf = (float*)d_ws;
    float* prebuf = wsf;                               // B*T*DH floats (pre -> hs bf16)
    uint*  bt = (uint*)(wsf + (size_t)BB * TT * DH);   // 788 tiles * 256 dwords

    Srcs s;
    s.p[0] = W_loc;  s.p[1] = W_scale; s.p[2] = gW1; s.p[3] = pW1;
    s.p[4] = gW2;    s.p[5] = pW2;     s.p[6] = lW;  s.p[7] = sW;
    s.p[8] = eW1;    s.p[9] = eW2;     s.p[10] = eW3; s.p[11] = W_ih; s.p[12] = W_hh;
    packall_kernel<<<788, 256, 0, stream>>>(s, bt);

    pre_kernel<<<dim3(TT / 16, BB), 256, 0, stream>>>(x, bt, b_ih, b_hh, prebuf);

    size_t smem = 27136 + 51712 + 13312;   // 92160 B
    hipFuncSetAttribute((const void*)rnn_kernel,
                        hipFuncAttributeMaxDynamicSharedMemorySize, (int)smem);
    rnn_kernel<<<dim3(8), dim3(512), smem, stream>>>((const u32x4*)bt, h0, prebuf);

    e_kernel<<<dim3(TT / 16, BB), 256, 0, stream>>>(
        (const uint4*)prebuf, eps, z0, bt,
        b_loc, b_scale, gb1, pb1, gb2, pb2, lb, sb, eb1, eb2, eb3,
        (float*)d_out);
}